// Round 4
// baseline (340.605 us; speedup 1.0000x reference)
//
#include <hip/hip_runtime.h>
#include <cstdint>
#include <cstddef>

typedef _Float16 f16;
typedef _Float16 f16x8 __attribute__((ext_vector_type(8)));
typedef float f32x4 __attribute__((ext_vector_type(4)));

// ---------------- helpers ----------------

__device__ __forceinline__ void gload16(const void* g, void* l) {
  // async global->LDS, 16B per lane; LDS dest must be wave-uniform base + lane*16
  __builtin_amdgcn_global_load_lds((const __attribute__((address_space(1))) void*)g,
                                   (__attribute__((address_space(3))) void*)l, 16, 0, 0);
}

__device__ __forceinline__ uint32_t packh2(float a, float b) {
  f16 ha = (f16)a, hb = (f16)b;
  uint16_t ua = __builtin_bit_cast(uint16_t, ha);
  uint16_t ub = __builtin_bit_cast(uint16_t, hb);
  return (uint32_t)ua | ((uint32_t)ub << 16);
}

// ---------------- prep: LUT^T fp16, centroid sq-norms, BN consts, pool zero ----------------
// lutT[o][c*16+k] = sum_s cent[c,k,s] * wsub[c,s,o]
__global__ __launch_bounds__(256) void prep_kernel(
    const float* __restrict__ cent1, const float* __restrict__ wsub1,
    const float* __restrict__ cent2, const float* __restrict__ wsub2,
    const float* __restrict__ g1, const float* __restrict__ be1,
    const float* __restrict__ mu1, const float* __restrict__ va1,
    const float* __restrict__ g2, const float* __restrict__ be2,
    const float* __restrict__ mu2, const float* __restrict__ va2,
    f16* __restrict__ lut1T, f16* __restrict__ lut2T,
    float* __restrict__ cn1, float* __restrict__ cn2,
    float* __restrict__ bn1i, float* __restrict__ bn1a,
    float* __restrict__ bn2i, float* __restrict__ bn2a,
    float* __restrict__ pool)
{
  int bx = blockIdx.x, t = threadIdx.x;
  if (bx < 8192) {
    int conv = bx >> 12, ck = bx & 4095, c = ck >> 4;
    const float* cent = conv ? cent2 : cent1;
    const float* wsub = conv ? wsub2 : wsub1;
    f16* lutT = conv ? lut2T : lut1T;
    float s = 0.f;
#pragma unroll
    for (int sv = 0; sv < 9; ++sv)
      s += cent[ck*9 + sv] * wsub[(c*9 + sv)*256 + t];
    lutT[(size_t)t*4096 + ck] = (f16)s;
  } else {
    for (int j = 0; j < 16; ++j) {
      int ck = j*256 + t;
      float s1 = 0.f, s2 = 0.f;
#pragma unroll
      for (int sv = 0; sv < 9; ++sv) {
        float a = cent1[ck*9 + sv]; s1 += a*a;
        float b = cent2[ck*9 + sv]; s2 += b*b;
      }
      cn1[ck] = s1; cn2[ck] = s2;
      pool[ck] = 0.f;                 // ws is re-poisoned 0xAA every launch
    }
    float i1 = g1[t] * rsqrtf(va1[t] + 1e-5f);
    bn1i[t] = i1; bn1a[t] = be1[t] - mu1[t]*i1;
    float i2 = g2[t] * rsqrtf(va2[t] + 1e-5f);
    bn2i[t] = i2; bn2a[t] = be2[t] - mu2[t]*i2;
  }
}

// ---------------- attention (soft codeword assignment) ----------------
// SRC==0: src is x, NCHW [16][256][28][28]. SRC==1: src is y1, NHWC [16*784][256].
// Thread = one spatial position; block handles ONE channel-pair (c0 = 2*blockIdx.y).
template<int SRC>
__global__ __launch_bounds__(256) void attn_kernel(
    const float* __restrict__ src, const float* __restrict__ cent,
    const float* __restrict__ cn, f16* __restrict__ attn)
{
  __shared__ uint32_t sbuf[16*256];   // [j][t] swizzle: conflict-free both phases
  int t = threadIdx.x;
  int P = blockIdx.x*256 + t;         // 0..12543
  int b = P / 784, n = P % 784, h = n / 28, w = n % 28;
  int c0 = blockIdx.y*2;
  int offc[9]; float msk[9];
#pragma unroll
  for (int dh = 0; dh < 3; ++dh)
#pragma unroll
    for (int dw = 0; dw < 3; ++dw) {
      int hh = h + dh - 1, ww = w + dw - 1;
      bool ok = (hh >= 0) && (hh < 28) && (ww >= 0) && (ww < 28);
      offc[dh*3+dw] = ok ? (hh*28 + ww) : 0;
      msk[dh*3+dw] = ok ? 1.f : 0.f;
    }
#pragma unroll
  for (int cc = 0; cc < 2; ++cc) {
    int c = c0 + cc;
    float p[9];
#pragma unroll
    for (int s = 0; s < 9; ++s) {
      float v;
      if (SRC == 0) v = src[(size_t)(b*256 + c)*784 + offc[s]];
      else          v = src[((size_t)b*784 + offc[s])*256 + c];
      p[s] = v * msk[s];
    }
    float e[16];
#pragma unroll
    for (int k = 0; k < 16; ++k) {
      const float* ce = cent + (size_t)(c*16 + k)*9;
      float dot = 0.f;
#pragma unroll
      for (int s = 0; s < 9; ++s) dot += p[s]*ce[s];
      e[k] = 2.f*dot - cn[c*16 + k];   // ||p||^2 cancels in softmax
    }
    float mx = e[0];
#pragma unroll
    for (int k = 1; k < 16; ++k) mx = fmaxf(mx, e[k]);
    float sum = 0.f;
#pragma unroll
    for (int k = 0; k < 16; ++k) { e[k] = __expf(e[k] - mx); sum += e[k]; }
    float r = 1.f / sum;
#pragma unroll
    for (int j = 0; j < 8; ++j)
      sbuf[(cc*8 + j)*256 + t] = packh2(e[2*j]*r, e[2*j+1]*r);
  }
  __syncthreads();
  // write phase: 4 lanes complete one 64B line (one position's 32 fp16)
  int seg = t & 3;
#pragma unroll
  for (int i = 0; i < 4; ++i) {
    int r = i*64 + (t >> 2);
    uint4 v = make_uint4(sbuf[(seg*4+0)*256 + r], sbuf[(seg*4+1)*256 + r],
                         sbuf[(seg*4+2)*256 + r], sbuf[(seg*4+3)*256 + r]);
    *(uint4*)(attn + (size_t)(blockIdx.x*256 + r)*4096 + c0*16 + seg*8) = v;
  }
}

// ---------------- GEMM: C[12544,256] = A[12544,4096] * BT[256,4096]^T, fused BN (+ReLU) ----------------
// BM=64, BN=64, BK=128, 256 threads (4 waves).
// 4-way wave K-split: wave w computes the FULL 64x64 tile over k-quarter w of
// each BK tile (4x4 acc per wave); 3-step cross-wave LDS reduction at end.
// XOR swizzle: LDS physical 16B-chunk p of row r holds logical chunk p^(r&7);
// bank group = chunk mod 8 -> per quarter-wave all 8 groups hit by 2 lanes
// (2-way = free, m136).
template<bool RELU>
__global__ __launch_bounds__(256, 3) void gemm_kernel(
    const f16* __restrict__ A, const f16* __restrict__ BT,
    const float* __restrict__ inv, const float* __restrict__ add,
    float* __restrict__ Cout)
{
  __shared__ __align__(16) f16 smem[2*64*128];  // As = smem (16KB), Bs = +8192 (16KB)
  f16* As = smem;
  f16* Bs = smem + 8192;
  int bx = blockIdx.x;
  int xcd = bx & 7, i = bx >> 3;
  int nt4 = i & 3, j = i >> 2;
  int mt = xcd + 8*j;                 // same-A blocks (4 n-tiles) share an XCD for L2 reuse
  if (mt >= 196) return;
  int row0 = mt*64, col0 = nt4*64;
  int t = threadIdx.x;
  int lane = t & 63, wave = t >> 6;   // wave == k-quarter owner
  int fm = lane & 15, fq = lane >> 4;

  // staging: thread t -> row t>>4 (per round +16), physical chunk t&15,
  // global logical chunk (t&15)^((t>>4)&7)
  int jg = (t & 15) ^ ((t >> 4) & 7);
  const f16* Ag = A  + (size_t)(row0 + (t >> 4))*4096 + jg*8;
  const f16* Bg = BT + (size_t)(col0 + (t >> 4))*4096 + jg*8;
  f16* Al = As + t*8;                 // == base + lane*16B within each wave's chunk
  f16* Bl = Bs + t*8;

  f32x4 acc[4][4] = {};

  // fragment read: row fm+16*m2 (row&7 == fm&7), logical chunk wave*4+fq
  int coff = (((wave*4 + fq)) ^ (fm & 7)) * 8;
  const f16* a_rd = As + fm*128 + coff;
  const f16* b_rd = Bs + fm*128 + coff;

  for (int kt = 0; kt < 32; ++kt) {
    int kb = kt*128;
#pragma unroll
    for (int ii = 0; ii < 4; ++ii) {
      gload16(Ag + (size_t)(ii*16)*4096 + kb, Al + ii*2048);
      gload16(Bg + (size_t)(ii*16)*4096 + kb, Bl + ii*2048);
    }
    __syncthreads();
    f16x8 af[4], bf[4];
#pragma unroll
    for (int m2 = 0; m2 < 4; ++m2) af[m2] = *(const f16x8*)(a_rd + m2*16*128);
#pragma unroll
    for (int nt = 0; nt < 4; ++nt) bf[nt] = *(const f16x8*)(b_rd + nt*16*128);
#pragma unroll
    for (int m2 = 0; m2 < 4; ++m2)
#pragma unroll
      for (int nt = 0; nt < 4; ++nt)
        acc[m2][nt] = __builtin_amdgcn_mfma_f32_16x16x32_f16(af[m2], bf[nt], acc[m2][nt], 0, 0, 0);
    __syncthreads();
  }

  // cross-wave K reduction (4 partials -> wave 0), via 2x 16KB LDS buffers
  float* red = (float*)smem;          // red0 = smem, red1 = smem+16KB
  if (wave >= 2) {
    float* dst = red + (wave - 2)*4096;
#pragma unroll
    for (int m2 = 0; m2 < 4; ++m2)
#pragma unroll
      for (int nt = 0; nt < 4; ++nt)
#pragma unroll
        for (int r = 0; r < 4; ++r)
          dst[(m2*16 + fq*4 + r)*64 + nt*16 + fm] = acc[m2][nt][r];
  }
  __syncthreads();
  if (wave < 2) {
    const float* s = red + wave*4096;
#pragma unroll
    for (int m2 = 0; m2 < 4; ++m2)
#pragma unroll
      for (int nt = 0; nt < 4; ++nt)
#pragma unroll
        for (int r = 0; r < 4; ++r)
          acc[m2][nt][r] += s[(m2*16 + fq*4 + r)*64 + nt*16 + fm];
  }
  __syncthreads();
  if (wave == 1) {
#pragma unroll
    for (int m2 = 0; m2 < 4; ++m2)
#pragma unroll
      for (int nt = 0; nt < 4; ++nt)
#pragma unroll
        for (int r = 0; r < 4; ++r)
          red[(m2*16 + fq*4 + r)*64 + nt*16 + fm] = acc[m2][nt][r];
  }
  __syncthreads();
  if (wave == 0) {
#pragma unroll
    for (int nt = 0; nt < 4; ++nt) {
      int colg = col0 + nt*16 + fm;   // C/D: col = lane&15
      float iv = inv[colg], ad = add[colg];
#pragma unroll
      for (int m2 = 0; m2 < 4; ++m2) {
        int rowl = m2*16 + fq*4;      // C/D: row = quad*4 + reg
#pragma unroll
        for (int r = 0; r < 4; ++r) {
          float v = (acc[m2][nt][r] + red[(rowl + r)*64 + nt*16 + fm])*iv + ad;
          if (RELU) v = fmaxf(v, 0.f);
          Cout[(size_t)(row0 + rowl + r)*256 + colg] = v;
        }
      }
    }
  }
}

// ---------------- global average pool (partial sums, atomics) ----------------
__global__ __launch_bounds__(256) void pool_kernel(const float* __restrict__ y2,
                                                   float* __restrict__ pool)
{
  int b = blockIdx.x, t = threadIdx.x;
  int r0 = blockIdx.y * 112;
  float s = 0.f;
  for (int r = 0; r < 112; ++r)
    s += y2[((size_t)b*784 + r0 + r)*256 + t];
  atomicAdd(&pool[b*256 + t], s);
}

// ---------------- SE MLP: scale = sigmoid(relu(mean @ w1 + b1) @ w2 + b2) ----------------
__global__ __launch_bounds__(256) void se_kernel(
    const float* __restrict__ pool, const float* __restrict__ w1, const float* __restrict__ b1,
    const float* __restrict__ w2, const float* __restrict__ b2, float* __restrict__ scale)
{
  __shared__ float m[256];
  __shared__ float hbuf[16];
  int b = blockIdx.x, t = threadIdx.x;
  m[t] = pool[b*256 + t] * (1.f/784.f);
  __syncthreads();
  if (t < 16) {
    float a = b1[t];
    for (int o = 0; o < 256; ++o) a += m[o]*w1[o*16 + t];
    hbuf[t] = fmaxf(a, 0.f);
  }
  __syncthreads();
  float a = b2[t];
#pragma unroll
  for (int jj = 0; jj < 16; ++jj) a += hbuf[jj]*w2[jj*256 + t];
  scale[b*256 + t] = 1.f/(1.f + __expf(-a));
}

// ---------------- final: out = relu(y2 * scale + x), NCHW ----------------
__global__ __launch_bounds__(256) void final_kernel(
    const float* __restrict__ y2, const float* __restrict__ scale,
    const float* __restrict__ x, float* __restrict__ out)
{
  int idx = blockIdx.x*256 + threadIdx.x;
  int b = idx / 200704, rem = idx % 200704;
  int o = rem / 784, hw = rem % 784;
  float v = y2[((size_t)b*784 + hw)*256 + o]*scale[b*256 + o] + x[idx];
  out[idx] = fmaxf(v, 0.f);
}

// ---------------- launch ----------------
extern "C" void kernel_launch(void* const* d_in, const int* in_sizes, int n_in,
                              void* d_out, int out_size, void* d_ws, size_t ws_size,
                              hipStream_t stream) {
  const float* x     = (const float*)d_in[0];
  const float* cent1 = (const float*)d_in[1];
  const float* wsub1 = (const float*)d_in[2];
  const float* g1    = (const float*)d_in[3];
  const float* be1   = (const float*)d_in[4];
  const float* mu1   = (const float*)d_in[5];
  const float* va1   = (const float*)d_in[6];
  const float* cent2 = (const float*)d_in[7];
  const float* wsub2 = (const float*)d_in[8];
  const float* g2    = (const float*)d_in[9];
  const float* be2   = (const float*)d_in[10];
  const float* mu2   = (const float*)d_in[11];
  const float* va2   = (const float*)d_in[12];
  const float* sw1   = (const float*)d_in[13];
  const float* sb1   = (const float*)d_in[14];
  const float* sw2   = (const float*)d_in[15];
  const float* sb2   = (const float*)d_in[16];
  float* out = (float*)d_out;

  char* ws = (char*)d_ws;
  f16*   attn  = (f16*)(ws + 0);                  // 12544*4096*2 = 102,760,448
  f16*   lut1T = (f16*)(ws + 102760448);          // 2 MB
  f16*   lut2T = (f16*)(ws + 104857600);          // 2 MB
  float* y1    = (float*)(ws + 106954752);        // 12,845,056
  float* y2    = (float*)(ws + 119799808);        // 12,845,056
  float* cn1   = (float*)(ws + 132644864);        // 16 KB
  float* cn2   = (float*)(ws + 132661248);        // 16 KB
  float* bn1i  = (float*)(ws + 132677632);
  float* bn1a  = (float*)(ws + 132678656);
  float* bn2i  = (float*)(ws + 132679680);
  float* bn2a  = (float*)(ws + 132680704);
  float* pool  = (float*)(ws + 132681728);        // 16 KB
  float* scale = (float*)(ws + 132698112);        // 16 KB  (end ~126.6 MiB)

  prep_kernel<<<8193, 256, 0, stream>>>(cent1, wsub1, cent2, wsub2,
                                        g1, be1, mu1, va1, g2, be2, mu2, va2,
                                        lut1T, lut2T, cn1, cn2,
                                        bn1i, bn1a, bn2i, bn2a, pool);
  attn_kernel<0><<<dim3(49, 128), 256, 0, stream>>>(x, cent1, cn1, attn);
  gemm_kernel<true><<<800, 256, 0, stream>>>(attn, lut1T, bn1i, bn1a, y1);
  attn_kernel<1><<<dim3(49, 128), 256, 0, stream>>>(y1, cent2, cn2, attn);
  gemm_kernel<false><<<800, 256, 0, stream>>>(attn, lut2T, bn2i, bn2a, y2);
  pool_kernel<<<dim3(16, 7), 256, 0, stream>>>(y2, pool);
  se_kernel<<<16, 256, 0, stream>>>(pool, sw1, sb1, sw2, sb2, scale);
  final_kernel<<<12544, 256, 0, stream>>>(y2, scale, x, out);
}

// Round 5
// 312.905 us; speedup vs baseline: 1.0885x; 1.0885x over previous
//
#include <hip/hip_runtime.h>
#include <cstdint>
#include <cstddef>

typedef _Float16 f16;
typedef _Float16 f16x8 __attribute__((ext_vector_type(8)));
typedef float f32x4 __attribute__((ext_vector_type(4)));

// ---------------- helpers ----------------

__device__ __forceinline__ void gload16(const void* g, void* l) {
  // async global->LDS, 16B per lane; LDS dest must be wave-uniform base + lane*16
  __builtin_amdgcn_global_load_lds((const __attribute__((address_space(1))) void*)g,
                                   (__attribute__((address_space(3))) void*)l, 16, 0, 0);
}

__device__ __forceinline__ uint32_t packh2(float a, float b) {
  f16 ha = (f16)a, hb = (f16)b;
  uint16_t ua = __builtin_bit_cast(uint16_t, ha);
  uint16_t ub = __builtin_bit_cast(uint16_t, hb);
  return (uint32_t)ua | ((uint32_t)ub << 16);
}

// ---------------- prep: LUT^T fp16, centroid sq-norms, BN consts, pool zero ----------------
// lutT[o][c*16+k] = sum_s cent[c,k,s] * wsub[c,s,o]
__global__ __launch_bounds__(256) void prep_kernel(
    const float* __restrict__ cent1, const float* __restrict__ wsub1,
    const float* __restrict__ cent2, const float* __restrict__ wsub2,
    const float* __restrict__ g1, const float* __restrict__ be1,
    const float* __restrict__ mu1, const float* __restrict__ va1,
    const float* __restrict__ g2, const float* __restrict__ be2,
    const float* __restrict__ mu2, const float* __restrict__ va2,
    f16* __restrict__ lut1T, f16* __restrict__ lut2T,
    float* __restrict__ cn1, float* __restrict__ cn2,
    float* __restrict__ bn1i, float* __restrict__ bn1a,
    float* __restrict__ bn2i, float* __restrict__ bn2a,
    float* __restrict__ pool)
{
  int bx = blockIdx.x, t = threadIdx.x;
  if (bx < 8192) {
    int conv = bx >> 12, ck = bx & 4095, c = ck >> 4;
    const float* cent = conv ? cent2 : cent1;
    const float* wsub = conv ? wsub2 : wsub1;
    f16* lutT = conv ? lut2T : lut1T;
    float s = 0.f;
#pragma unroll
    for (int sv = 0; sv < 9; ++sv)
      s += cent[ck*9 + sv] * wsub[(c*9 + sv)*256 + t];
    lutT[(size_t)t*4096 + ck] = (f16)s;
  } else {
    for (int j = 0; j < 16; ++j) {
      int ck = j*256 + t;
      float s1 = 0.f, s2 = 0.f;
#pragma unroll
      for (int sv = 0; sv < 9; ++sv) {
        float a = cent1[ck*9 + sv]; s1 += a*a;
        float b = cent2[ck*9 + sv]; s2 += b*b;
      }
      cn1[ck] = s1; cn2[ck] = s2;
      pool[ck] = 0.f;                 // ws is re-poisoned 0xAA every launch
    }
    float i1 = g1[t] * rsqrtf(va1[t] + 1e-5f);
    bn1i[t] = i1; bn1a[t] = be1[t] - mu1[t]*i1;
    float i2 = g2[t] * rsqrtf(va2[t] + 1e-5f);
    bn2i[t] = i2; bn2a[t] = be2[t] - mu2[t]*i2;
  }
}

// ---------------- attention (soft codeword assignment) ----------------
// SRC==0: src is x, NCHW [16][256][28][28]. SRC==1: src is y1, NHWC [16*784][256].
// Thread = one spatial position; block handles ONE channel-pair (c0 = 2*blockIdx.y).
template<int SRC>
__global__ __launch_bounds__(256) void attn_kernel(
    const float* __restrict__ src, const float* __restrict__ cent,
    const float* __restrict__ cn, f16* __restrict__ attn)
{
  __shared__ uint32_t sbuf[16*256];   // [j][t] swizzle: conflict-free both phases
  int t = threadIdx.x;
  int P = blockIdx.x*256 + t;         // 0..12543
  int b = P / 784, n = P % 784, h = n / 28, w = n % 28;
  int c0 = blockIdx.y*2;
  int offc[9]; float msk[9];
#pragma unroll
  for (int dh = 0; dh < 3; ++dh)
#pragma unroll
    for (int dw = 0; dw < 3; ++dw) {
      int hh = h + dh - 1, ww = w + dw - 1;
      bool ok = (hh >= 0) && (hh < 28) && (ww >= 0) && (ww < 28);
      offc[dh*3+dw] = ok ? (hh*28 + ww) : 0;
      msk[dh*3+dw] = ok ? 1.f : 0.f;
    }
  float p2[2][9];
  if (SRC == 1) {
#pragma unroll
    for (int s = 0; s < 9; ++s) {
      float2 v = *(const float2*)(src + ((size_t)b*784 + offc[s])*256 + c0);
      p2[0][s] = v.x * msk[s];
      p2[1][s] = v.y * msk[s];
    }
  }
#pragma unroll
  for (int cc = 0; cc < 2; ++cc) {
    int c = c0 + cc;
    float p[9];
#pragma unroll
    for (int s = 0; s < 9; ++s) {
      if (SRC == 0) p[s] = src[(size_t)(b*256 + c)*784 + offc[s]] * msk[s];
      else          p[s] = p2[cc][s];
    }
    float e[16];
#pragma unroll
    for (int k = 0; k < 16; ++k) {
      const float* ce = cent + (size_t)(c*16 + k)*9;
      float dot = 0.f;
#pragma unroll
      for (int s = 0; s < 9; ++s) dot += p[s]*ce[s];
      e[k] = 2.f*dot - cn[c*16 + k];   // ||p||^2 cancels in softmax
    }
    float mx = e[0];
#pragma unroll
    for (int k = 1; k < 16; ++k) mx = fmaxf(mx, e[k]);
    float sum = 0.f;
#pragma unroll
    for (int k = 0; k < 16; ++k) { e[k] = __expf(e[k] - mx); sum += e[k]; }
    float r = 1.f / sum;
#pragma unroll
    for (int j = 0; j < 8; ++j)
      sbuf[(cc*8 + j)*256 + t] = packh2(e[2*j]*r, e[2*j+1]*r);
  }
  __syncthreads();
  // write phase: 4 lanes complete one 64B line (one position's 32 fp16)
  int seg = t & 3;
#pragma unroll
  for (int i = 0; i < 4; ++i) {
    int r = i*64 + (t >> 2);
    uint4 v = make_uint4(sbuf[(seg*4+0)*256 + r], sbuf[(seg*4+1)*256 + r],
                         sbuf[(seg*4+2)*256 + r], sbuf[(seg*4+3)*256 + r]);
    *(uint4*)(attn + (size_t)(blockIdx.x*256 + r)*4096 + c0*16 + seg*8) = v;
  }
}

// ---------------- GEMM: C[12544,256] = A[12544,4096] * BT[256,4096]^T, fused BN (+ReLU) ----------------
// BM=128, BN=128, BK=64, 256 threads (4 waves as 2x2; each wave 64x64 full-K,
// no cross-wave reduction). LDS double-buffered (2x32KB): K-loop is
// {sync; prefetch next->bufB; compute bufA} so the barrier's implicit vmcnt(0)
// drains loads that had a full compute phase to land -> staging overlapped.
// XOR swizzle: physical 16B-chunk p of row r holds logical chunk p^(r&7);
// readers offset by fm&7 -> 2 lanes/bank-group (free, m136).
template<bool RELU>
__global__ __launch_bounds__(256, 2) void gemm_kernel(
    const f16* __restrict__ A, const f16* __restrict__ BT,
    const float* __restrict__ inv, const float* __restrict__ add,
    float* __restrict__ Cout)
{
  __shared__ __align__(16) f16 smem[4*8192];    // buf0:{A,B} buf1:{A,B}, 16KB each half
  f16* As0 = smem;
  f16* Bs0 = smem + 8192;
  f16* As1 = smem + 16384;
  f16* Bs1 = smem + 24576;

  // grid 208 = 16 x 13; xcd = bx&7 stable within a (mt, nt) pair -> same-A
  // pairs share an XCD's L2 (B is 2MB total, fits per-XCD L2 whole).
  int bx = blockIdx.x;
  int xw = bx & 7, nt = (bx >> 3) & 1, g = bx >> 4;
  int mt = xw + 8*g;
  if (mt >= 98) return;
  int row0 = mt*128, col0 = nt*128;

  int t = threadIdx.x;
  int lane = t & 63, wave = t >> 6;
  int wm = wave >> 1, wn = wave & 1;  // 2x2 wave grid, wave tile 64x64
  int fm = lane & 15, fq = lane >> 4;

  // staging: thread t -> row (t>>3)+32*ii, physical chunk t&7,
  // global logical chunk (t&7)^((t>>3)&7); 4 rounds each for A and B.
  int jg = (t & 7) ^ ((t >> 3) & 7);
  const f16* Ag = A  + (size_t)(row0 + (t >> 3))*4096 + jg*8;
  const f16* Bg = BT + (size_t)(col0 + (t >> 3))*4096 + jg*8;

  f32x4 acc[4][4] = {};

  auto stage = [&](f16* Ab, f16* Bb, int kb) {
#pragma unroll
    for (int ii = 0; ii < 4; ++ii) {
      gload16(Ag + (size_t)(ii*32)*4096 + kb, Ab + t*8 + ii*2048);
      gload16(Bg + (size_t)(ii*32)*4096 + kb, Bb + t*8 + ii*2048);
    }
  };
  auto compute = [&](const f16* Ab, const f16* Bb) {
#pragma unroll
    for (int ks = 0; ks < 2; ++ks) {
      int co = ((ks*4 + fq) ^ (fm & 7)) * 8;
      f16x8 af[4], bf[4];
#pragma unroll
      for (int m2 = 0; m2 < 4; ++m2)
        af[m2] = *(const f16x8*)(Ab + (wm*64 + m2*16 + fm)*64 + co);
#pragma unroll
      for (int n2 = 0; n2 < 4; ++n2)
        bf[n2] = *(const f16x8*)(Bb + (wn*64 + n2*16 + fm)*64 + co);
#pragma unroll
      for (int m2 = 0; m2 < 4; ++m2)
#pragma unroll
        for (int n2 = 0; n2 < 4; ++n2)
          acc[m2][n2] = __builtin_amdgcn_mfma_f32_16x16x32_f16(af[m2], bf[n2], acc[m2][n2], 0, 0, 0);
    }
  };

  stage(As0, Bs0, 0);                  // prologue: tile 0
#pragma unroll 1
  for (int kt2 = 0; kt2 < 32; ++kt2) {
    __syncthreads();                   // tile 2k landed; buf1 free (prev compute done)
    stage(As1, Bs1, (2*kt2 + 1)*64);   // prefetch tile 2k+1
    compute(As0, Bs0);                 // compute tile 2k
    __syncthreads();                   // tile 2k+1 landed; buf0 free
    if (kt2 < 31) stage(As0, Bs0, (2*kt2 + 2)*64);
    compute(As1, Bs1);                 // compute tile 2k+1
  }

  // epilogue: direct write (full-K per wave, no reduction)
#pragma unroll
  for (int n2 = 0; n2 < 4; ++n2) {
    int colg = col0 + wn*64 + n2*16 + fm;     // C/D: col = lane&15
    float iv = inv[colg], ad = add[colg];
#pragma unroll
    for (int m2 = 0; m2 < 4; ++m2) {
      int rowg = row0 + wm*64 + m2*16 + fq*4; // C/D: row = quad*4 + reg
#pragma unroll
      for (int r = 0; r < 4; ++r) {
        float v = acc[m2][n2][r]*iv + ad;
        if (RELU) v = fmaxf(v, 0.f);
        Cout[(size_t)(rowg + r)*256 + colg] = v;
      }
    }
  }
}

// ---------------- global average pool (partial sums, atomics) ----------------
__global__ __launch_bounds__(256) void pool_kernel(const float* __restrict__ y2,
                                                   float* __restrict__ pool)
{
  int b = blockIdx.x, t = threadIdx.x;
  int r0 = blockIdx.y * 112;
  float s = 0.f;
  for (int r = 0; r < 112; ++r)
    s += y2[((size_t)b*784 + r0 + r)*256 + t];
  atomicAdd(&pool[b*256 + t], s);
}

// ---------------- SE MLP: scale = sigmoid(relu(mean @ w1 + b1) @ w2 + b2) ----------------
__global__ __launch_bounds__(256) void se_kernel(
    const float* __restrict__ pool, const float* __restrict__ w1, const float* __restrict__ b1,
    const float* __restrict__ w2, const float* __restrict__ b2, float* __restrict__ scale)
{
  __shared__ float m[256];
  __shared__ float hbuf[16];
  int b = blockIdx.x, t = threadIdx.x;
  m[t] = pool[b*256 + t] * (1.f/784.f);
  __syncthreads();
  if (t < 16) {
    float a = b1[t];
    for (int o = 0; o < 256; ++o) a += m[o]*w1[o*16 + t];
    hbuf[t] = fmaxf(a, 0.f);
  }
  __syncthreads();
  float a = b2[t];
#pragma unroll
  for (int jj = 0; jj < 16; ++jj) a += hbuf[jj]*w2[jj*256 + t];
  scale[b*256 + t] = 1.f/(1.f + __expf(-a));
}

// ---------------- final: out = relu(y2 * scale + x), NCHW ----------------
__global__ __launch_bounds__(256) void final_kernel(
    const float* __restrict__ y2, const float* __restrict__ scale,
    const float* __restrict__ x, float* __restrict__ out)
{
  int idx = blockIdx.x*256 + threadIdx.x;
  int b = idx / 200704, rem = idx % 200704;
  int o = rem / 784, hw = rem % 784;
  float v = y2[((size_t)b*784 + hw)*256 + o]*scale[b*256 + o] + x[idx];
  out[idx] = fmaxf(v, 0.f);
}

// ---------------- launch ----------------
extern "C" void kernel_launch(void* const* d_in, const int* in_sizes, int n_in,
                              void* d_out, int out_size, void* d_ws, size_t ws_size,
                              hipStream_t stream) {
  const float* x     = (const float*)d_in[0];
  const float* cent1 = (const float*)d_in[1];
  const float* wsub1 = (const float*)d_in[2];
  const float* g1    = (const float*)d_in[3];
  const float* be1   = (const float*)d_in[4];
  const float* mu1   = (const float*)d_in[5];
  const float* va1   = (const float*)d_in[6];
  const float* cent2 = (const float*)d_in[7];
  const float* wsub2 = (const float*)d_in[8];
  const float* g2    = (const float*)d_in[9];
  const float* be2   = (const float*)d_in[10];
  const float* mu2   = (const float*)d_in[11];
  const float* va2   = (const float*)d_in[12];
  const float* sw1   = (const float*)d_in[13];
  const float* sb1   = (const float*)d_in[14];
  const float* sw2   = (const float*)d_in[15];
  const float* sb2   = (const float*)d_in[16];
  float* out = (float*)d_out;

  char* ws = (char*)d_ws;
  f16*   attn  = (f16*)(ws + 0);                  // 12544*4096*2 = 102,760,448
  f16*   lut1T = (f16*)(ws + 102760448);          // 2 MB
  f16*   lut2T = (f16*)(ws + 104857600);          // 2 MB
  float* y1    = (float*)(ws + 106954752);        // 12,845,056
  float* y2    = (float*)(ws + 119799808);        // 12,845,056
  float* cn1   = (float*)(ws + 132644864);        // 16 KB
  float* cn2   = (float*)(ws + 132661248);        // 16 KB
  float* bn1i  = (float*)(ws + 132677632);
  float* bn1a  = (float*)(ws + 132678656);
  float* bn2i  = (float*)(ws + 132679680);
  float* bn2a  = (float*)(ws + 132680704);
  float* pool  = (float*)(ws + 132681728);        // 16 KB
  float* scale = (float*)(ws + 132698112);        // 16 KB  (end ~126.6 MiB)

  prep_kernel<<<8193, 256, 0, stream>>>(cent1, wsub1, cent2, wsub2,
                                        g1, be1, mu1, va1, g2, be2, mu2, va2,
                                        lut1T, lut2T, cn1, cn2,
                                        bn1i, bn1a, bn2i, bn2a, pool);
  attn_kernel<0><<<dim3(49, 128), 256, 0, stream>>>(x, cent1, cn1, attn);
  gemm_kernel<true><<<208, 256, 0, stream>>>(attn, lut1T, bn1i, bn1a, y1);
  attn_kernel<1><<<dim3(49, 128), 256, 0, stream>>>(y1, cent2, cn2, attn);
  gemm_kernel<false><<<208, 256, 0, stream>>>(attn, lut2T, bn2i, bn2a, y2);
  pool_kernel<<<dim3(16, 7), 256, 0, stream>>>(y2, pool);
  se_kernel<<<16, 256, 0, stream>>>(pool, sw1, sb1, sw2, sb2, scale);
  final_kernel<<<12544, 256, 0, stream>>>(y2, scale, x, out);
}